// Round 15
// baseline (299.452 us; speedup 1.0000x reference)
//
#include <hip/hip_runtime.h>
#include <math.h>

typedef unsigned short u16;
typedef unsigned int u32;
typedef __attribute__((ext_vector_type(8))) short short8;
typedef __attribute__((ext_vector_type(4))) float f32x4;
typedef __attribute__((ext_vector_type(4))) unsigned short ushort4v;

#define B_ 8
#define S_ 2048
#define D_ 2048
#define H_ 16
#define RLEN 4194304   // S_*D_ elems per batch sample
#define NCHUNK 512

static __device__ __forceinline__ u16 f2bf(float f) {
    union { float f; u32 u; } v; v.f = f;
    u32 r = v.u + 0x7fffu + ((v.u >> 16) & 1u);
    return (u16)(r >> 16);
}
static __device__ __forceinline__ float bf2f(u16 u) {
    union { u32 u; float f; } v; v.u = ((u32)u) << 16;
    return v.f;
}
// fast tanh-GELU (|err| <= ~3e-3 vs exact, within bf16 budget)
static __device__ __forceinline__ float gelu_fast(float v) {
    float z = 1.5957691216057308f * v * (1.0f + 0.044715f * v * v);
    float e = __expf(z);
    float r = __builtin_amdgcn_rcpf(e + 1.0f);
    return v * (1.0f - r);
}
// non-temporal float4 load via clang ext-vector (HIP_vector_type not accepted)
static __device__ __forceinline__ f32x4 ntload4(const float* p) {
    return __builtin_nontemporal_load((const f32x4*)p);
}

typedef const __attribute__((address_space(1))) u32* gas1_t;
typedef __attribute__((address_space(3))) u32* las3_t;
static __device__ __forceinline__ void gload_lds16(const void* g, void* l) {
    __builtin_amdgcn_global_load_lds((gas1_t)g, (las3_t)l, 16, 0, 0);
}

// ---------------- Kernel 1: router partial dots (+ fused x->bf16 swizzled) --
template<int XB>
__global__ __launch_bounds__(256, 3) void router_partial(const float* __restrict__ x,
                                                         const float* __restrict__ sw,
                                                         float* __restrict__ part,
                                                         u16* __restrict__ xb) {
    int c = blockIdx.x;
    int t = threadIdx.x;
    const int chunk = RLEN / NCHUNK;        // 8192
    int base = c * chunk;
    float acc[8][8];
#pragma unroll
    for (int b = 0; b < 8; b++)
#pragma unroll
        for (int e = 0; e < 8; e++) acc[b][e] = 0.f;

    for (int it = 0; it < chunk / (256 * 4); ++it) {   // 8 iterations
        int i = base + (it * 256 + t) * 4;
        f32x4 xv[8];
#pragma unroll
        for (int b = 0; b < 8; b++) xv[b] = ntload4(&x[(size_t)b * RLEN + i]);
        if (XB) {
            int row = i >> 7, col = i & 127;
            int scol = (((col >> 3) ^ (row & 7)) << 3) | (col & 7);
#pragma unroll
            for (int b = 0; b < 8; b++) {
                ushort4v u;
                u.x = f2bf(xv[b].x); u.y = f2bf(xv[b].y);
                u.z = f2bf(xv[b].z); u.w = f2bf(xv[b].w);
                *(ushort4v*)&xb[(size_t)b * RLEN + (size_t)row * 128 + scol] = u;
            }
        }
        f32x4 sv = ntload4(&sw[i]);
#pragma unroll
        for (int e = 0; e < 8; e++) {
            f32x4 svn;
            if (e < 7) svn = ntload4(&sw[(size_t)(e + 1) * RLEN + i]);
#pragma unroll
            for (int b = 0; b < 8; b++)
                acc[b][e] += xv[b].x * sv.x + xv[b].y * sv.y +
                             xv[b].z * sv.z + xv[b].w * sv.w;
            sv = svn;
        }
    }

    __shared__ float red[4][64];
    int lane = t & 63, wv = t >> 6;
#pragma unroll
    for (int q = 0; q < 64; q++) {
        float v = acc[q >> 3][q & 7];
#pragma unroll
        for (int m = 32; m >= 1; m >>= 1) v += __shfl_xor(v, m, 64);
        if (lane == 0) red[wv][q] = v;
    }
    __syncthreads();
    if (t < 64) {
        float s = red[0][t] + red[1][t] + red[2][t] + red[3][t];
        part[(size_t)t * NCHUNK + c] = s;
    }
}

// ---------------- Kernel 2: reduce + softmax + top-2 + combined b2 bias ----
__global__ __launch_bounds__(512) void router_finish(const float* __restrict__ part,
                                                     const float* __restrict__ swb,
                                                     const float* __restrict__ b2,
                                                     float* __restrict__ gate,
                                                     int* __restrict__ idx,
                                                     float* __restrict__ bc) {
    int t = threadIdx.x;
    __shared__ float lg[64];
    __shared__ float sg[16];
    __shared__ int   si[16];
    {
        int row = t >> 3, seg = t & 7;
        const float* p = part + (size_t)row * NCHUNK + seg * 64;
        float s = 0.f;
#pragma unroll 8
        for (int c = 0; c < 64; c++) s += p[c];
#pragma unroll
        for (int m = 4; m >= 1; m >>= 1) s += __shfl_down(s, m, 64);
        if (seg == 0) lg[row] = s + swb[row & 7];
    }
    __syncthreads();
    if (t < 8) {
        int b = t;
        float m = -1e30f;
        for (int e = 0; e < 8; e++) m = fmaxf(m, lg[b * 8 + e]);
        float p[8]; float sum = 0.f;
        for (int e = 0; e < 8; e++) { p[e] = expf(lg[b * 8 + e] - m); sum += p[e]; }
        for (int e = 0; e < 8; e++) p[e] /= sum;
        int i1 = 0; float v1 = p[0];
        for (int e = 1; e < 8; e++) if (p[e] > v1) { v1 = p[e]; i1 = e; }
        int i2 = -1; float v2 = -1.f;
        for (int e = 0; e < 8; e++) if (e != i1 && p[e] > v2) { v2 = p[e]; i2 = e; }
        gate[b * 2 + 0] = v1; gate[b * 2 + 1] = v2;
        idx[b * 2 + 0] = i1;  idx[b * 2 + 1] = i2;
        sg[b * 2] = v1; sg[b * 2 + 1] = v2;
        si[b * 2] = i1; si[b * 2 + 1] = i2;
    }
    __syncthreads();
    if (t < 128)
        for (int b = 0; b < 8; b++)
            bc[b * 128 + t] = sg[b * 2] * b2[si[b * 2] * 128 + t] +
                              sg[b * 2 + 1] * b2[si[b * 2 + 1] * 128 + t];
}

// ---------------- Kernel 3a: w1/w2 -> bf16 (w1 swizzled) -------------------
__global__ __launch_bounds__(256) void convert_w12(const float* __restrict__ w1,
                                                   const float* __restrict__ w2,
                                                   u16* __restrict__ w1b,
                                                   u16* __restrict__ w2b) {
    int i4 = (blockIdx.x * 256 + threadIdx.x) * 4;
    if (i4 < 131072) {
        int k = i4 & 127, f = (i4 >> 7) & 127;
        float4 v = *(const float4*)&w1[i4];
        int sc = ((((k >> 3) ^ (f & 7)) << 3) | (k & 7));
        ushort4v u;
        u.x = f2bf(v.x); u.y = f2bf(v.y); u.z = f2bf(v.z); u.w = f2bf(v.w);
        *(ushort4v*)&w1b[(i4 & ~127) + sc] = u;
    } else {
        int j = i4 - 131072;
        float4 v = *(const float4*)&w2[j];
        ushort4v u;
        u.x = f2bf(v.x); u.y = f2bf(v.y); u.z = f2bf(v.z); u.w = f2bf(v.w);
        *(ushort4v*)&w2b[j] = u;
    }
}

// ---------------- Kernel 3b: w3 -> bf16 ------------------------------------
__global__ __launch_bounds__(256) void convert_w3(const float* __restrict__ w3,
                                                  u16* __restrict__ w3b) {
    size_t i = ((size_t)blockIdx.x * 256 + threadIdx.x) * 4;
    float4 v = *(const float4*)&w3[i];
    u16* d = &w3b[i];
    d[0] = f2bf(v.x); d[1] = f2bf(v.y); d[2] = f2bf(v.z); d[3] = f2bf(v.w);
}

// ---------------- Kernel 4: expert MLP v5 — W1 AND W2 fragments in regs ----
template<int XB>
__global__ __launch_bounds__(512) void mlp_kernel(const void* __restrict__ xsrc_,
                                                  const u16* __restrict__ w1b,
                                                  const u16* __restrict__ w2b,
                                                  const float* __restrict__ b1,
                                                  const float* __restrict__ gate,
                                                  const int* __restrict__ idx,
                                                  const float* __restrict__ bc,
                                                  u16* __restrict__ y) {
    __shared__ __align__(16) u16 xs[2][64 * 128];  // 32 KB
    __shared__ __align__(16) u16 hb[2][32 * 256];  // 32 KB
    __shared__ __align__(16) u16 ob[2][32 * 128];  // 16 KB  (80 KB total)
    const int t = threadIdx.x, lane = t & 63, w = t >> 6;
    const int wr = w >> 2, wq = w & 3;
    const int l15 = lane & 15, l4 = lane >> 4;
    const int b = blockIdx.y, grp = blockIdx.x;
    const size_t xbase = (size_t)b * RLEN;
    const size_t gbase = xbase + (size_t)grp * 65536;
    const int e0 = idx[b * 2], e1 = idx[b * 2 + 1];
    const int slot = wq >> 1;
    const int esel = slot ? e1 : e0;
    const float gw = gate[b * 2 + slot];
    const float* b1p = b1 + esel * 128;

    float b1v[4];
#pragma unroll
    for (int nt = 0; nt < 4; nt++) b1v[nt] = b1p[(wq & 1) * 64 + nt * 16 + l15];
    float bcv[2];
#pragma unroll
    for (int n = 0; n < 2; n++) bcv[n] = bc[b * 128 + wq * 32 + n * 16 + l15];

    // W1' fragments in registers (from swizzled w1b; (fr&7) == (l15&7))
    short8 w1f[4][4];   // [nt][kb]
#pragma unroll
    for (int nt = 0; nt < 4; nt++)
#pragma unroll
        for (int kb = 0; kb < 4; kb++) {
            int kg = kb * 4 + l4;
            int fr = (wq & 1) * 64 + nt * 16 + l15;
            w1f[nt][kb] = *(const short8*)&w1b[((size_t)(esel * 128 + fr)) * 128 +
                                               ((kg ^ (l15 & 7)) << 3)];
        }
    // W2' fragments in registers
    short8 w2f[2][8];
#pragma unroll
    for (int n = 0; n < 2; n++) {
        int d = wq * 32 + n * 16 + l15;
#pragma unroll
        for (int kb = 0; kb < 8; kb++) {
            int e = (kb >= 4) ? e1 : e0;
            int f = (kb & 3) * 32 + l4 * 8;
            w2f[n][kb] = *(const short8*)&w2b[((size_t)(e * 128 + d)) * 128 + f];
        }
    }

    if (XB) {
        const u16* xbp = (const u16*)xsrc_;
#pragma unroll
        for (int T = 0; T < 2; T++) {
            gload_lds16(xbp + gbase + T * 8192 + t * 8, (char*)&xs[T][0] + t * 16);
            gload_lds16(xbp + gbase + T * 8192 + 4096 + t * 8,
                        (char*)&xs[T][0] + 8192 + t * 16);
        }
        asm volatile("s_waitcnt vmcnt(0)" ::: "memory");
    } else {
        const float* xf = (const float*)xsrc_;
#pragma unroll
        for (int T = 0; T < 2; T++)
#pragma unroll
            for (int p = 0; p < 4; p++) {
                int elem = p * 2048 + t * 4;
                int row = elem >> 7, col = elem & 127;
                float4 v = *(const float4*)&xf[gbase + T * 8192 + elem];
                ushort4v u;
                u.x = f2bf(v.x); u.y = f2bf(v.y); u.z = f2bf(v.z); u.w = f2bf(v.w);
                *(ushort4v*)((char*)&xs[T][0] + row * 256 +
                             (((col >> 3) ^ (row & 7)) << 4) + (col & 7) * 2) = u;
            }
        asm volatile("s_waitcnt vmcnt(0) lgkmcnt(0)" ::: "memory");
    }
    __builtin_amdgcn_s_barrier();

    auto G1 = [&](int st, f32x4* a1) {
        const u16* xc = &xs[(st >> 1) & 1][0];
        int rbase = (st & 1) * 32 + wr * 16 + l15;
#pragma unroll
        for (int nt = 0; nt < 4; nt++) a1[nt] = (f32x4){0.f, 0.f, 0.f, 0.f};
#pragma unroll
        for (int kb = 0; kb < 4; kb++) {
            int kg = kb * 4 + l4;
            short8 a = *(const short8*)&xc[rbase * 128 + ((kg ^ (rbase & 7)) << 3)];
#pragma unroll
            for (int nt = 0; nt < 4; nt++)
                a1[nt] = __builtin_amdgcn_mfma_f32_16x16x32_bf16(a, w1f[nt][kb], a1[nt], 0, 0, 0);
        }
    };
    auto GELU_ST = [&](int st, f32x4* a1) {
        u16* hd = &hb[st & 1][0];
#pragma unroll
        for (int nt = 0; nt < 4; nt++) {
            int fcol = wq * 64 + nt * 16 + l15;
#pragma unroll
            for (int j = 0; j < 4; j++) {
                int row = wr * 16 + l4 * 4 + j;
                float v = a1[nt][j] + b1v[nt];
                v = gelu_fast(v) * gw;
                hd[row * 256 + ((((fcol >> 3) ^ (row & 7)) << 3) | (fcol & 7))] = f2bf(v);
            }
        }
    };
    auto G2 = [&](int st, f32x4* a2) {
        const u16* hs = &hb[st & 1][0];
        int arow = wr * 16 + l15;
        a2[0] = (f32x4){0.f, 0.f, 0.f, 0.f};
        a2[1] = (f32x4){0.f, 0.f, 0.f, 0.f};
#pragma unroll
        for (int kb = 0; kb < 8; kb++) {
            int fg = kb * 4 + l4;
            short8 a = *(const short8*)&hs[arow * 256 + ((fg ^ (arow & 7)) << 3)];
            a2[0] = __builtin_amdgcn_mfma_f32_16x16x32_bf16(a, w2f[0][kb], a2[0], 0, 0, 0);
            a2[1] = __builtin_amdgcn_mfma_f32_16x16x32_bf16(a, w2f[1][kb], a2[1], 0, 0, 0);
        }
    };
    auto OWRITE = [&](int st, f32x4* a2) {
        u16* od = &ob[st & 1][0];
        const u16* xc = &xs[(st >> 1) & 1][0];
#pragma unroll
        for (int n = 0; n < 2; n++) {
            int d = wq * 32 + n * 16 + l15;
#pragma unroll
            for (int j = 0; j < 4; j++) {
                int row = wr * 16 + l4 * 4 + j;
                int xrow = (st & 1) * 32 + row;
                float xr = bf2f(xc[xrow * 128 + ((((d >> 3) ^ (xrow & 7)) << 3) | (d & 7))]);
                od[row * 128 + (d ^ ((row & 7) << 3))] = f2bf(a2[n][j] + bcv[n] + xr);
            }
        }
    };
    auto YSTV = [&](int st) {
        int row = t >> 4;
        int cg = t & 15;
        const u16* os = &ob[st & 1][0];
        short8 v = *(const short8*)&os[row * 128 + ((cg ^ (row & 7)) << 3)];
        u16* yb = y + xbase + (size_t)grp * 65536 + st * 4096;
        *(short8*)&yb[row * 128 + cg * 8] = v;
    };

    {
        f32x4 a1[4];
        G1(0, a1);
        GELU_ST(0, a1);
    }
    asm volatile("s_waitcnt lgkmcnt(0)" ::: "memory");
    __builtin_amdgcn_s_barrier();

    for (int st = 0; st < 17; ++st) {
        const bool stg = (st < 16) && ((st & 1) == 0) && st >= 2 && st <= 12;
        if (st < 16) {
            f32x4 a1n[4];
            if (st < 15) G1(st + 1, a1n);
            f32x4 a2[2];
            G2(st, a2);
            if (st < 15) GELU_ST(st + 1, a1n);
            OWRITE(st, a2);
        }
        if (stg) {
            int T = st / 2 + 1;
            if (XB) {
                const u16* xbp = (const u16*)xsrc_;
                gload_lds16(xbp + gbase + T * 8192 + t * 8, (char*)&xs[T & 1][0] + t * 16);
                gload_lds16(xbp + gbase + T * 8192 + 4096 + t * 8,
                            (char*)&xs[T & 1][0] + 8192 + t * 16);
            } else {
                const float* xf = (const float*)xsrc_;
#pragma unroll
                for (int p = 0; p < 4; p++) {
                    int elem = p * 2048 + t * 4;
                    int row = elem >> 7, col = elem & 127;
                    float4 v = *(const float4*)&xf[gbase + T * 8192 + elem];
                    ushort4v u;
                    u.x = f2bf(v.x); u.y = f2bf(v.y); u.z = f2bf(v.z); u.w = f2bf(v.w);
                    *(ushort4v*)((char*)&xs[T & 1][0] + row * 256 +
                                 (((col >> 3) ^ (row & 7)) << 4) + (col & 7) * 2) = u;
                }
            }
        }
        if (st >= 1) YSTV(st - 1);
        asm volatile("s_waitcnt lgkmcnt(0)" ::: "memory");
        if (stg && XB) asm volatile("s_waitcnt vmcnt(1)" ::: "memory");
        if (st < 16) __builtin_amdgcn_s_barrier();
    }
}

// ---------------- Kernel 5: out = y @ w3^T + b3, 256^2 BK=32, 2 blocks/CU --
// R6 pipelined schedule scaled to BK=32: 64KB LDS (2buf x A/B 16KB) -> two
// independent blocks per CU overlap each other's barrier/vmcnt stalls (m114).
// Row-strip XCD swizzle (FETCH ~100MB). 4-slot x (row&3) XOR swizzle: 64-lane
// b128 read = 2-way bank aliasing (free). 4 staging loads/K-tile; vmcnt(4)
// prologue, vmcnt(0) rendezvous (tile tt+1's 4 loads drained).
#define BARX() do { asm volatile("" ::: "memory"); __builtin_amdgcn_s_barrier(); \
                    asm volatile("" ::: "memory"); } while (0)

#define WLG(NSTR) do { asm volatile("s_waitcnt lgkmcnt(" NSTR ")" ::: "memory"); \
                       __builtin_amdgcn_sched_barrier(0); } while (0)

#define DSA(mh, c) do { \
    const char* _ba = smem + (c) * 32768 + abase; \
    _Pragma("unroll") for (int mf = 0; mf < 4; mf++) \
        areg[mf] = *(const short8*)(_ba + ((mh) * 4 + mf) * 1024 + kof); \
} while (0)

#define DSB(nh, c) do { \
    const char* _bb = smem + (c) * 32768 + bbase; \
    _Pragma("unroll") for (int nf = 0; nf < 2; nf++) \
        breg[(nh) * 2 + nf] = *(const short8*)(_bb + ((nh) * 2 + nf) * 1024 + kof); \
} while (0)

#define MMAQ(mh, nh) do { \
    __builtin_amdgcn_s_setprio(1); \
    _Pragma("unroll") for (int mf = 0; mf < 4; mf++) \
    _Pragma("unroll") for (int nf = 0; nf < 2; nf++) \
        acc[(mh) * 4 + mf][(nh) * 2 + nf] = __builtin_amdgcn_mfma_f32_16x16x32_bf16( \
            areg[mf], breg[(nh) * 2 + nf], acc[(mh) * 4 + mf][(nh) * 2 + nf], 0, 0, 0); \
    __builtin_amdgcn_s_setprio(0); \
} while (0)

// one 16B load per thread: 256 rows x 32 cols staged per op per K-tile
#define STG(op, c, kt) do { \
    const u16* _gs = (op) ? wbp : yap; \
    int _tr0 = (op) ? nrow0 : mrow0; \
    int _row = t >> 2; \
    int _h = t >> 9; /* 0 */ \
    int _gcol = (((t & 3) ^ (_row & 3)) << 3); \
    gload_lds16(_gs + (size_t)(_tr0 + (op##_half) * 0 + _row) * 2048 + (kt) * 32 + _gcol, \
                smem + (c) * 32768 + (op) * 16384 + t * 16); \
    (void)_h; \
} while (0)

// ^ STG stages rows 0..127 only (t>>2 max 127 at t=511). Need 256 rows -> two
//   halves: h from t>>8? 512 threads x 16B = 8KB = 128 rows. So per op we need
//   2 STG calls with explicit h. Redefine cleanly:
#undef STG
#define STG(op, c, h, kt) do { \
    const u16* _gs = (op) ? wbp : yap; \
    int _tr0 = (op) ? nrow0 : mrow0; \
    int _idx = t; \
    int _row = _idx >> 2; \
    int _gcol = (((_idx & 3) ^ (_row & 3)) << 3); \
    gload_lds16(_gs + (size_t)(_tr0 + (h) * 128 + _row) * 2048 + (kt) * 32 + _gcol, \
                smem + (c) * 32768 + (op) * 16384 + (h) * 8192 + _idx * 16); \
} while (0)

__global__ __launch_bounds__(512, 2) void final_gemm256(const u16* __restrict__ yap,
                                                        const u16* __restrict__ wbp,
                                                        const float* __restrict__ b3,
                                                        float* __restrict__ out) {
    extern __shared__ char smem[];
    const int t = threadIdx.x;
    const int lane = t & 63, w = t >> 6;
    const int wm = w >> 2, wn = w & 3;
    const int l15 = lane & 15, l4 = lane >> 4;

    // Row-strip XCD swizzle: XCD (bid&7) owns mblk in [8k, 8k+8), nblk fast.
    int bid = blockIdx.x;
    int xcd = bid & 7, q = bid >> 3;
    const int mrow0 = (xcd * 8 + (q >> 3)) * 256;
    const int nrow0 = (q & 7) * 256;

    // A: 16KB = 2 halves x (128 rows x 64B); B likewise at +16KB.
    const int abase = wm * 8192 + l15 * 64;
    const int bbase = 16384 + (wn >> 1) * 8192 + ((wn & 1) * 64 + l15) * 64;
    const int kof = ((l4 ^ (l15 & 3)) << 4);

    f32x4 acc[8][4];
#pragma unroll
    for (int m = 0; m < 8; m++)
#pragma unroll
        for (int n = 0; n < 4; n++) acc[m][n] = (f32x4){0.f, 0.f, 0.f, 0.f};
    short8 areg[4];
    short8 breg[4];

    // prologue: T0 -> buf0 (4 loads), T1 -> buf1 (4 loads); wait T0
    STG(0, 0, 0, 0); STG(0, 0, 1, 0); STG(1, 0, 0, 0); STG(1, 0, 1, 0);
    STG(0, 1, 0, 1); STG(0, 1, 1, 1); STG(1, 1, 0, 1); STG(1, 1, 1, 1);
    asm volatile("s_waitcnt vmcnt(4)" ::: "memory");
    BARX();
    DSA(0, 0); DSB(0, 0); DSB(1, 0);   // 8 reads in flight

    for (int it2 = 0; it2 < 32; ++it2) {
#pragma unroll
        for (int c = 0; c < 2; ++c) {
            const int tt = 2 * it2 + c;
            WLG("2");  MMAQ(0, 0);             // A0(4)+B0(2) = oldest 6
            WLG("0");  MMAQ(0, 1);             // +B1
            DSA(1, c);                          // A1 (4 reads), hidden
            WLG("0");  MMAQ(1, 0);
            asm volatile("s_waitcnt vmcnt(0)" ::: "memory");
            BARX();
            if (tt < 62) { STG(0, c, 0, tt + 2); STG(0, c, 1, tt + 2);
                           STG(1, c, 0, tt + 2); STG(1, c, 1, tt + 2); }
            MMAQ(1, 1);
            if (tt < 63) { DSA(0, c ^ 1); DSB(0, c ^ 1); DSB(1, c ^ 1); }
        }
    }

#pragma unroll
    for (int m = 0; m < 8; m++)
#pragma unroll
        for (int n = 0; n < 4; n++) {
            int col = nrow0 + wn * 64 + n * 16 + l15;
            float bias = b3[col];
            int row = mrow0 + wm * 128 + m * 16 + l4 * 4;
#pragma unroll
            for (int j = 0; j < 4; j++)
                out[(size_t)(row + j) * 2048 + col] = acc[m][n][j] + bias;
        }
}

// ---------------------------------------------------------------------------
extern "C" void kernel_launch(void* const* d_in, const int* in_sizes, int n_in,
                              void* d_out, int out_size, void* d_ws, size_t ws_size,
                              hipStream_t stream) {
    const float* x   = (const float*)d_in[0];
    const float* sw  = (const float*)d_in[1];
    const float* swb = (const float*)d_in[2];
    const float* w1  = (const float*)d_in[3];
    const float* b1  = (const float*)d_in[4];
    const float* w2  = (const float*)d_in[5];
    const float* b2  = (const float*)d_in[6];
    const float* w3  = (const float*)d_in[7];
    const float* b3  = (const float*)d_in[8];
    float* out = (float*)d_out;

    char* ws = (char*)d_ws;
    float* part = (float*)(ws + 0);                 // 128 KB
    float* gate = (float*)(ws + 131072);            // 64 B
    int*   idx  = (int*)(ws + 131136);              // 64 B
    float* bc   = (float*)(ws + 131200);            // 4 KB
    u16*   w1b  = (u16*)(ws + 262144);              // 256 KB (swizzled)
    u16*   w2b  = (u16*)(ws + 524288);              // 256 KB
    u16*   w3b  = (u16*)(ws + 786432);              // 8 MB
    u16*   y    = (u16*)(ws + 9175040);             // 64 MB
    u16*   xb   = (u16*)(ws + 76283904);            // 64 MB (swizzled bf16 x)
    const size_t need_xb = 143392768;
    const bool xbmode = ws_size >= need_xb;

    hipFuncSetAttribute((const void*)final_gemm256,
                        hipFuncAttributeMaxDynamicSharedMemorySize, 65536);

    if (xbmode)
        hipLaunchKernelGGL((router_partial<1>), dim3(NCHUNK), dim3(256), 0, stream, x, sw, part, xb);
    else
        hipLaunchKernelGGL((router_partial<0>), dim3(NCHUNK), dim3(256), 0, stream, x, sw, part, xb);
    hipLaunchKernelGGL(router_finish, dim3(1), dim3(512), 0, stream, part, swb, b2, gate, idx, bc);
    hipLaunchKernelGGL(convert_w12, dim3(256), dim3(256), 0, stream, w1, w2, w1b, w2b);
    hipLaunchKernelGGL(convert_w3, dim3(D_ * D_ / 1024), dim3(256), 0, stream, w3, w3b);
    if (xbmode)
        hipLaunchKernelGGL((mlp_kernel<1>), dim3(64, 8), dim3(512), 0, stream,
                           (const void*)xb, w1b, w2b, b1, gate, idx, bc, y);
    else
        hipLaunchKernelGGL((mlp_kernel<0>), dim3(64, 8), dim3(512), 0, stream,
                           (const void*)x, w1b, w2b, b1, gate, idx, bc, y);
    hipLaunchKernelGGL(final_gemm256, dim3(512), dim3(512), 65536, stream,
                       y, w3b, b3, out);
}

// Round 16
// 287.490 us; speedup vs baseline: 1.0416x; 1.0416x over previous
//
#include <hip/hip_runtime.h>
#include <math.h>

typedef unsigned short u16;
typedef unsigned int u32;
typedef __attribute__((ext_vector_type(8))) short short8;
typedef __attribute__((ext_vector_type(4))) float f32x4;
typedef __attribute__((ext_vector_type(4))) unsigned short ushort4v;

#define B_ 8
#define S_ 2048
#define D_ 2048
#define H_ 16
#define RLEN 4194304   // S_*D_ elems per batch sample
#define NCHUNK 512

static __device__ __forceinline__ u16 f2bf(float f) {
    union { float f; u32 u; } v; v.f = f;
    u32 r = v.u + 0x7fffu + ((v.u >> 16) & 1u);
    return (u16)(r >> 16);
}
static __device__ __forceinline__ float bf2f(u16 u) {
    union { u32 u; float f; } v; v.u = ((u32)u) << 16;
    return v.f;
}
// fast tanh-GELU (|err| <= ~3e-3 vs exact, within bf16 budget)
static __device__ __forceinline__ float gelu_fast(float v) {
    float z = 1.5957691216057308f * v * (1.0f + 0.044715f * v * v);
    float e = __expf(z);
    float r = __builtin_amdgcn_rcpf(e + 1.0f);
    return v * (1.0f - r);
}
// non-temporal float4 load via clang ext-vector (HIP_vector_type not accepted)
static __device__ __forceinline__ f32x4 ntload4(const float* p) {
    return __builtin_nontemporal_load((const f32x4*)p);
}

typedef const __attribute__((address_space(1))) u32* gas1_t;
typedef __attribute__((address_space(3))) u32* las3_t;
static __device__ __forceinline__ void gload_lds16(const void* g, void* l) {
    __builtin_amdgcn_global_load_lds((gas1_t)g, (las3_t)l, 16, 0, 0);
}

// ---------------- Kernel 1: router partial dots (+ fused x->bf16 swizzled) --
template<int XB>
__global__ __launch_bounds__(256, 3) void router_partial(const float* __restrict__ x,
                                                         const float* __restrict__ sw,
                                                         float* __restrict__ part,
                                                         u16* __restrict__ xb) {
    int c = blockIdx.x;
    int t = threadIdx.x;
    const int chunk = RLEN / NCHUNK;        // 8192
    int base = c * chunk;
    float acc[8][8];
#pragma unroll
    for (int b = 0; b < 8; b++)
#pragma unroll
        for (int e = 0; e < 8; e++) acc[b][e] = 0.f;

    for (int it = 0; it < chunk / (256 * 4); ++it) {   // 8 iterations
        int i = base + (it * 256 + t) * 4;
        f32x4 xv[8];
#pragma unroll
        for (int b = 0; b < 8; b++) xv[b] = ntload4(&x[(size_t)b * RLEN + i]);
        if (XB) {
            int row = i >> 7, col = i & 127;
            int scol = (((col >> 3) ^ (row & 7)) << 3) | (col & 7);
#pragma unroll
            for (int b = 0; b < 8; b++) {
                ushort4v u;
                u.x = f2bf(xv[b].x); u.y = f2bf(xv[b].y);
                u.z = f2bf(xv[b].z); u.w = f2bf(xv[b].w);
                *(ushort4v*)&xb[(size_t)b * RLEN + (size_t)row * 128 + scol] = u;
            }
        }
        f32x4 sv = ntload4(&sw[i]);
#pragma unroll
        for (int e = 0; e < 8; e++) {
            f32x4 svn;
            if (e < 7) svn = ntload4(&sw[(size_t)(e + 1) * RLEN + i]);
#pragma unroll
            for (int b = 0; b < 8; b++)
                acc[b][e] += xv[b].x * sv.x + xv[b].y * sv.y +
                             xv[b].z * sv.z + xv[b].w * sv.w;
            sv = svn;
        }
    }

    __shared__ float red[4][64];
    int lane = t & 63, wv = t >> 6;
#pragma unroll
    for (int q = 0; q < 64; q++) {
        float v = acc[q >> 3][q & 7];
#pragma unroll
        for (int m = 32; m >= 1; m >>= 1) v += __shfl_xor(v, m, 64);
        if (lane == 0) red[wv][q] = v;
    }
    __syncthreads();
    if (t < 64) {
        float s = red[0][t] + red[1][t] + red[2][t] + red[3][t];
        part[(size_t)t * NCHUNK + c] = s;
    }
}

// ---------------- Kernel 2: reduce + softmax + top-2 + combined b2 bias ----
__global__ __launch_bounds__(512) void router_finish(const float* __restrict__ part,
                                                     const float* __restrict__ swb,
                                                     const float* __restrict__ b2,
                                                     float* __restrict__ gate,
                                                     int* __restrict__ idx,
                                                     float* __restrict__ bc) {
    int t = threadIdx.x;
    __shared__ float lg[64];
    __shared__ float sg[16];
    __shared__ int   si[16];
    {
        int row = t >> 3, seg = t & 7;
        const float* p = part + (size_t)row * NCHUNK + seg * 64;
        float s = 0.f;
#pragma unroll 8
        for (int c = 0; c < 64; c++) s += p[c];
#pragma unroll
        for (int m = 4; m >= 1; m >>= 1) s += __shfl_down(s, m, 64);
        if (seg == 0) lg[row] = s + swb[row & 7];
    }
    __syncthreads();
    if (t < 8) {
        int b = t;
        float m = -1e30f;
        for (int e = 0; e < 8; e++) m = fmaxf(m, lg[b * 8 + e]);
        float p[8]; float sum = 0.f;
        for (int e = 0; e < 8; e++) { p[e] = expf(lg[b * 8 + e] - m); sum += p[e]; }
        for (int e = 0; e < 8; e++) p[e] /= sum;
        int i1 = 0; float v1 = p[0];
        for (int e = 1; e < 8; e++) if (p[e] > v1) { v1 = p[e]; i1 = e; }
        int i2 = -1; float v2 = -1.f;
        for (int e = 0; e < 8; e++) if (e != i1 && p[e] > v2) { v2 = p[e]; i2 = e; }
        gate[b * 2 + 0] = v1; gate[b * 2 + 1] = v2;
        idx[b * 2 + 0] = i1;  idx[b * 2 + 1] = i2;
        sg[b * 2] = v1; sg[b * 2 + 1] = v2;
        si[b * 2] = i1; si[b * 2 + 1] = i2;
    }
    __syncthreads();
    if (t < 128)
        for (int b = 0; b < 8; b++)
            bc[b * 128 + t] = sg[b * 2] * b2[si[b * 2] * 128 + t] +
                              sg[b * 2 + 1] * b2[si[b * 2 + 1] * 128 + t];
}

// ---------------- Kernel 3a: w1/w2 -> bf16 (w1 swizzled) -------------------
__global__ __launch_bounds__(256) void convert_w12(const float* __restrict__ w1,
                                                   const float* __restrict__ w2,
                                                   u16* __restrict__ w1b,
                                                   u16* __restrict__ w2b) {
    int i4 = (blockIdx.x * 256 + threadIdx.x) * 4;
    if (i4 < 131072) {
        int k = i4 & 127, f = (i4 >> 7) & 127;
        float4 v = *(const float4*)&w1[i4];
        int sc = ((((k >> 3) ^ (f & 7)) << 3) | (k & 7));
        ushort4v u;
        u.x = f2bf(v.x); u.y = f2bf(v.y); u.z = f2bf(v.z); u.w = f2bf(v.w);
        *(ushort4v*)&w1b[(i4 & ~127) + sc] = u;
    } else {
        int j = i4 - 131072;
        float4 v = *(const float4*)&w2[j];
        ushort4v u;
        u.x = f2bf(v.x); u.y = f2bf(v.y); u.z = f2bf(v.z); u.w = f2bf(v.w);
        *(ushort4v*)&w2b[j] = u;
    }
}

// ---------------- Kernel 3b: w3 -> bf16 ------------------------------------
__global__ __launch_bounds__(256) void convert_w3(const float* __restrict__ w3,
                                                  u16* __restrict__ w3b) {
    size_t i = ((size_t)blockIdx.x * 256 + threadIdx.x) * 4;
    float4 v = *(const float4*)&w3[i];
    u16* d = &w3b[i];
    d[0] = f2bf(v.x); d[1] = f2bf(v.y); d[2] = f2bf(v.z); d[3] = f2bf(v.w);
}

// ---------------- Kernel 4: expert MLP v5 — W1 AND W2 fragments in regs ----
template<int XB>
__global__ __launch_bounds__(512) void mlp_kernel(const void* __restrict__ xsrc_,
                                                  const u16* __restrict__ w1b,
                                                  const u16* __restrict__ w2b,
                                                  const float* __restrict__ b1,
                                                  const float* __restrict__ gate,
                                                  const int* __restrict__ idx,
                                                  const float* __restrict__ bc,
                                                  u16* __restrict__ y) {
    __shared__ __align__(16) u16 xs[2][64 * 128];  // 32 KB
    __shared__ __align__(16) u16 hb[2][32 * 256];  // 32 KB
    __shared__ __align__(16) u16 ob[2][32 * 128];  // 16 KB  (80 KB total)
    const int t = threadIdx.x, lane = t & 63, w = t >> 6;
    const int wr = w >> 2, wq = w & 3;
    const int l15 = lane & 15, l4 = lane >> 4;
    const int b = blockIdx.y, grp = blockIdx.x;
    const size_t xbase = (size_t)b * RLEN;
    const size_t gbase = xbase + (size_t)grp * 65536;
    const int e0 = idx[b * 2], e1 = idx[b * 2 + 1];
    const int slot = wq >> 1;
    const int esel = slot ? e1 : e0;
    const float gw = gate[b * 2 + slot];
    const float* b1p = b1 + esel * 128;

    float b1v[4];
#pragma unroll
    for (int nt = 0; nt < 4; nt++) b1v[nt] = b1p[(wq & 1) * 64 + nt * 16 + l15];
    float bcv[2];
#pragma unroll
    for (int n = 0; n < 2; n++) bcv[n] = bc[b * 128 + wq * 32 + n * 16 + l15];

    // W1' fragments in registers (from swizzled w1b; (fr&7) == (l15&7))
    short8 w1f[4][4];   // [nt][kb]
#pragma unroll
    for (int nt = 0; nt < 4; nt++)
#pragma unroll
        for (int kb = 0; kb < 4; kb++) {
            int kg = kb * 4 + l4;
            int fr = (wq & 1) * 64 + nt * 16 + l15;
            w1f[nt][kb] = *(const short8*)&w1b[((size_t)(esel * 128 + fr)) * 128 +
                                               ((kg ^ (l15 & 7)) << 3)];
        }
    // W2' fragments in registers
    short8 w2f[2][8];
#pragma unroll
    for (int n = 0; n < 2; n++) {
        int d = wq * 32 + n * 16 + l15;
#pragma unroll
        for (int kb = 0; kb < 8; kb++) {
            int e = (kb >= 4) ? e1 : e0;
            int f = (kb & 3) * 32 + l4 * 8;
            w2f[n][kb] = *(const short8*)&w2b[((size_t)(e * 128 + d)) * 128 + f];
        }
    }

    if (XB) {
        const u16* xbp = (const u16*)xsrc_;
#pragma unroll
        for (int T = 0; T < 2; T++) {
            gload_lds16(xbp + gbase + T * 8192 + t * 8, (char*)&xs[T][0] + t * 16);
            gload_lds16(xbp + gbase + T * 8192 + 4096 + t * 8,
                        (char*)&xs[T][0] + 8192 + t * 16);
        }
        asm volatile("s_waitcnt vmcnt(0)" ::: "memory");
    } else {
        const float* xf = (const float*)xsrc_;
#pragma unroll
        for (int T = 0; T < 2; T++)
#pragma unroll
            for (int p = 0; p < 4; p++) {
                int elem = p * 2048 + t * 4;
                int row = elem >> 7, col = elem & 127;
                float4 v = *(const float4*)&xf[gbase + T * 8192 + elem];
                ushort4v u;
                u.x = f2bf(v.x); u.y = f2bf(v.y); u.z = f2bf(v.z); u.w = f2bf(v.w);
                *(ushort4v*)((char*)&xs[T][0] + row * 256 +
                             (((col >> 3) ^ (row & 7)) << 4) + (col & 7) * 2) = u;
            }
        asm volatile("s_waitcnt vmcnt(0) lgkmcnt(0)" ::: "memory");
    }
    __builtin_amdgcn_s_barrier();

    auto G1 = [&](int st, f32x4* a1) {
        const u16* xc = &xs[(st >> 1) & 1][0];
        int rbase = (st & 1) * 32 + wr * 16 + l15;
#pragma unroll
        for (int nt = 0; nt < 4; nt++) a1[nt] = (f32x4){0.f, 0.f, 0.f, 0.f};
#pragma unroll
        for (int kb = 0; kb < 4; kb++) {
            int kg = kb * 4 + l4;
            short8 a = *(const short8*)&xc[rbase * 128 + ((kg ^ (rbase & 7)) << 3)];
#pragma unroll
            for (int nt = 0; nt < 4; nt++)
                a1[nt] = __builtin_amdgcn_mfma_f32_16x16x32_bf16(a, w1f[nt][kb], a1[nt], 0, 0, 0);
        }
    };
    auto GELU_ST = [&](int st, f32x4* a1) {
        u16* hd = &hb[st & 1][0];
#pragma unroll
        for (int nt = 0; nt < 4; nt++) {
            int fcol = wq * 64 + nt * 16 + l15;
#pragma unroll
            for (int j = 0; j < 4; j++) {
                int row = wr * 16 + l4 * 4 + j;
                float v = a1[nt][j] + b1v[nt];
                v = gelu_fast(v) * gw;
                hd[row * 256 + ((((fcol >> 3) ^ (row & 7)) << 3) | (fcol & 7))] = f2bf(v);
            }
        }
    };
    auto G2 = [&](int st, f32x4* a2) {
        const u16* hs = &hb[st & 1][0];
        int arow = wr * 16 + l15;
        a2[0] = (f32x4){0.f, 0.f, 0.f, 0.f};
        a2[1] = (f32x4){0.f, 0.f, 0.f, 0.f};
#pragma unroll
        for (int kb = 0; kb < 8; kb++) {
            int fg = kb * 4 + l4;
            short8 a = *(const short8*)&hs[arow * 256 + ((fg ^ (arow & 7)) << 3)];
            a2[0] = __builtin_amdgcn_mfma_f32_16x16x32_bf16(a, w2f[0][kb], a2[0], 0, 0, 0);
            a2[1] = __builtin_amdgcn_mfma_f32_16x16x32_bf16(a, w2f[1][kb], a2[1], 0, 0, 0);
        }
    };
    auto OWRITE = [&](int st, f32x4* a2) {
        u16* od = &ob[st & 1][0];
        const u16* xc = &xs[(st >> 1) & 1][0];
#pragma unroll
        for (int n = 0; n < 2; n++) {
            int d = wq * 32 + n * 16 + l15;
#pragma unroll
            for (int j = 0; j < 4; j++) {
                int row = wr * 16 + l4 * 4 + j;
                int xrow = (st & 1) * 32 + row;
                float xr = bf2f(xc[xrow * 128 + ((((d >> 3) ^ (xrow & 7)) << 3) | (d & 7))]);
                od[row * 128 + (d ^ ((row & 7) << 3))] = f2bf(a2[n][j] + bcv[n] + xr);
            }
        }
    };
    auto YSTV = [&](int st) {
        int row = t >> 4;
        int cg = t & 15;
        const u16* os = &ob[st & 1][0];
        short8 v = *(const short8*)&os[row * 128 + ((cg ^ (row & 7)) << 3)];
        u16* yb = y + xbase + (size_t)grp * 65536 + st * 4096;
        *(short8*)&yb[row * 128 + cg * 8] = v;
    };

    {
        f32x4 a1[4];
        G1(0, a1);
        GELU_ST(0, a1);
    }
    asm volatile("s_waitcnt lgkmcnt(0)" ::: "memory");
    __builtin_amdgcn_s_barrier();

    for (int st = 0; st < 17; ++st) {
        const bool stg = (st < 16) && ((st & 1) == 0) && st >= 2 && st <= 12;
        if (st < 16) {
            f32x4 a1n[4];
            if (st < 15) G1(st + 1, a1n);
            f32x4 a2[2];
            G2(st, a2);
            if (st < 15) GELU_ST(st + 1, a1n);
            OWRITE(st, a2);
        }
        if (stg) {
            int T = st / 2 + 1;
            if (XB) {
                const u16* xbp = (const u16*)xsrc_;
                gload_lds16(xbp + gbase + T * 8192 + t * 8, (char*)&xs[T & 1][0] + t * 16);
                gload_lds16(xbp + gbase + T * 8192 + 4096 + t * 8,
                            (char*)&xs[T & 1][0] + 8192 + t * 16);
            } else {
                const float* xf = (const float*)xsrc_;
#pragma unroll
                for (int p = 0; p < 4; p++) {
                    int elem = p * 2048 + t * 4;
                    int row = elem >> 7, col = elem & 127;
                    float4 v = *(const float4*)&xf[gbase + T * 8192 + elem];
                    ushort4v u;
                    u.x = f2bf(v.x); u.y = f2bf(v.y); u.z = f2bf(v.z); u.w = f2bf(v.w);
                    *(ushort4v*)((char*)&xs[T & 1][0] + row * 256 +
                                 (((col >> 3) ^ (row & 7)) << 4) + (col & 7) * 2) = u;
                }
            }
        }
        if (st >= 1) YSTV(st - 1);
        asm volatile("s_waitcnt lgkmcnt(0)" ::: "memory");
        if (stg && XB) asm volatile("s_waitcnt vmcnt(1)" ::: "memory");
        if (st < 16) __builtin_amdgcn_s_barrier();
    }
}

// ---------------- Kernel 5: out = y @ w3^T + b3, 256^2 pipelined (R14) -----
// R6 schedule + row-strip XCD swizzle, BK=64, 128KB LDS, conflicts 0.
// (R15's BK=32 regressed: 64B rows allow only 4-slot swizzle -> structural
// 4-way bank conflict, 1.26e7 counted. BK=64 is the conflict-free point.)
#define BARX() do { asm volatile("" ::: "memory"); __builtin_amdgcn_s_barrier(); \
                    asm volatile("" ::: "memory"); } while (0)

#define WLG(NSTR) do { asm volatile("s_waitcnt lgkmcnt(" NSTR ")" ::: "memory"); \
                       __builtin_amdgcn_sched_barrier(0); } while (0)

#define DSA(mh, c) do { \
    const char* _ba = smem + (c) * 65536 + abase; \
    _Pragma("unroll") for (int mf = 0; mf < 4; mf++) \
    _Pragma("unroll") for (int kk = 0; kk < 2; kk++) \
        areg[mf][kk] = *(const short8*)(_ba + ((mh) * 4 + mf) * 2048 + kof[kk]); \
} while (0)

#define DSB(nh, c) do { \
    const char* _bb = smem + (c) * 65536 + bbase; \
    _Pragma("unroll") for (int nf = 0; nf < 2; nf++) \
    _Pragma("unroll") for (int kk = 0; kk < 2; kk++) \
        breg[(nh) * 2 + nf][kk] = *(const short8*)(_bb + ((nh) * 2 + nf) * 2048 + kof[kk]); \
} while (0)

#define MMAQ(mh, nh) do { \
    __builtin_amdgcn_s_setprio(1); \
    _Pragma("unroll") for (int mf = 0; mf < 4; mf++) \
    _Pragma("unroll") for (int nf = 0; nf < 2; nf++) \
    _Pragma("unroll") for (int kk = 0; kk < 2; kk++) \
        acc[(mh) * 4 + mf][(nh) * 2 + nf] = __builtin_amdgcn_mfma_f32_16x16x32_bf16( \
            areg[mf][kk], breg[(nh) * 2 + nf][kk], acc[(mh) * 4 + mf][(nh) * 2 + nf], 0, 0, 0); \
    __builtin_amdgcn_s_setprio(0); \
} while (0)

#define STG(op, c, h, kt) do { \
    const u16* _gs = (op) ? wbp : yap; \
    int _tr0 = (op) ? nrow0 : mrow0; \
    _Pragma("unroll") for (int p = 0; p < 2; p++) { \
        int _idx = p * 512 + t; \
        int _row = _idx >> 3; \
        int _gcol = (((_idx & 7) ^ (_row & 7)) << 3); \
        gload_lds16(_gs + (size_t)(_tr0 + (h) * 128 + _row) * 2048 + (kt) * 64 + _gcol, \
                    smem + (c) * 65536 + (op) * 32768 + (h) * 16384 + _idx * 16); \
    } \
} while (0)

__global__ __launch_bounds__(512, 2) void final_gemm256(const u16* __restrict__ yap,
                                                        const u16* __restrict__ wbp,
                                                        const float* __restrict__ b3,
                                                        float* __restrict__ out) {
    extern __shared__ char smem[];
    const int t = threadIdx.x;
    const int lane = t & 63, w = t >> 6;
    const int wm = w >> 2, wn = w & 3;
    const int l15 = lane & 15, l4 = lane >> 4, sx = lane & 7;

    // Row-strip XCD swizzle: XCD (bid&7) owns mblk in [8k, 8k+8), nblk fast.
    int bid = blockIdx.x;
    int xcd = bid & 7, q = bid >> 3;
    const int mrow0 = (xcd * 8 + (q >> 3)) * 256;
    const int nrow0 = (q & 7) * 256;

    const int abase = wm * 16384 + l15 * 128;
    const int bbase = 32768 + (wn >> 1) * 16384 + ((wn & 1) * 64 + l15) * 128;
    int kof[2];
#pragma unroll
    for (int kk = 0; kk < 2; kk++) kof[kk] = ((kk * 4 + l4) ^ sx) << 4;

    f32x4 acc[8][4];
#pragma unroll
    for (int m = 0; m < 8; m++)
#pragma unroll
        for (int n = 0; n < 4; n++) acc[m][n] = (f32x4){0.f, 0.f, 0.f, 0.f};
    short8 areg[4][2];
    short8 breg[4][2];

    STG(0, 0, 0, 0); STG(0, 0, 1, 0); STG(1, 0, 0, 0); STG(1, 0, 1, 0);
    STG(0, 1, 0, 1); STG(0, 1, 1, 1); STG(1, 1, 0, 1); STG(1, 1, 1, 1);
    asm volatile("s_waitcnt vmcnt(8)" ::: "memory");
    BARX();
    DSA(0, 0); DSB(0, 0); DSB(1, 0);

    for (int it2 = 0; it2 < 16; ++it2) {
#pragma unroll
        for (int c = 0; c < 2; ++c) {
            const int tt = 2 * it2 + c;
            WLG("4");  MMAQ(0, 0);
            WLG("0");  MMAQ(0, 1);
            DSA(1, c);
            WLG("0");  MMAQ(1, 0);
            asm volatile("s_waitcnt vmcnt(0)" ::: "memory");
            BARX();
            if (tt < 30) { STG(0, c, 0, tt + 2); STG(0, c, 1, tt + 2);
                           STG(1, c, 0, tt + 2); STG(1, c, 1, tt + 2); }
            MMAQ(1, 1);
            if (tt < 31) { DSA(0, c ^ 1); DSB(0, c ^ 1); DSB(1, c ^ 1); }
        }
    }

#pragma unroll
    for (int m = 0; m < 8; m++)
#pragma unroll
        for (int n = 0; n < 4; n++) {
            int col = nrow0 + wn * 64 + n * 16 + l15;
            float bias = b3[col];
            int row = mrow0 + wm * 128 + m * 16 + l4 * 4;
#pragma unroll
            for (int j = 0; j < 4; j++)
                out[(size_t)(row + j) * 2048 + col] = acc[m][n][j] + bias;
        }
}

// ---------------------------------------------------------------------------
extern "C" void kernel_launch(void* const* d_in, const int* in_sizes, int n_in,
                              void* d_out, int out_size, void* d_ws, size_t ws_size,
                              hipStream_t stream) {
    const float* x   = (const float*)d_in[0];
    const float* sw  = (const float*)d_in[1];
    const float* swb = (const float*)d_in[2];
    const float* w1  = (const float*)d_in[3];
    const float* b1  = (const float*)d_in[4];
    const float* w2  = (const float*)d_in[5];
    const float* b2  = (const float*)d_in[6];
    const float* w3  = (const float*)d_in[7];
    const float* b3  = (const float*)d_in[8];
    float* out = (float*)d_out;

    char* ws = (char*)d_ws;
    float* part = (float*)(ws + 0);                 // 128 KB
    float* gate = (float*)(ws + 131072);            // 64 B
    int*   idx  = (int*)(ws + 131136);              // 64 B
    float* bc   = (float*)(ws + 131200);            // 4 KB
    u16*   w1b  = (u16*)(ws + 262144);              // 256 KB (swizzled)
    u16*   w2b  = (u16*)(ws + 524288);              // 256 KB
    u16*   w3b  = (u16*)(ws + 786432);              // 8 MB
    u16*   y    = (u16*)(ws + 9175040);             // 64 MB
    u16*   xb   = (u16*)(ws + 76283904);            // 64 MB (swizzled bf16 x)
    const size_t need_xb = 143392768;
    const bool xbmode = ws_size >= need_xb;

    hipFuncSetAttribute((const void*)final_gemm256,
                        hipFuncAttributeMaxDynamicSharedMemorySize, 131072);

    if (xbmode)
        hipLaunchKernelGGL((router_partial<1>), dim3(NCHUNK), dim3(256), 0, stream, x, sw, part, xb);
    else
        hipLaunchKernelGGL((router_partial<0>), dim3(NCHUNK), dim3(256), 0, stream, x, sw, part, xb);
    hipLaunchKernelGGL(router_finish, dim3(1), dim3(512), 0, stream, part, swb, b2, gate, idx, bc);
    hipLaunchKernelGGL(convert_w12, dim3(256), dim3(256), 0, stream, w1, w2, w1b, w2b);
    hipLaunchKernelGGL(convert_w3, dim3(D_ * D_ / 1024), dim3(256), 0, stream, w3, w3b);
    if (xbmode)
        hipLaunchKernelGGL((mlp_kernel<1>), dim3(64, 8), dim3(512), 0, stream,
                           (const void*)xb, w1b, w2b, b1, gate, idx, bc, y);
    else
        hipLaunchKernelGGL((mlp_kernel<0>), dim3(64, 8), dim3(512), 0, stream,
                           (const void*)x, w1b, w2b, b1, gate, idx, bc, y);
    hipLaunchKernelGGL(final_gemm256, dim3(512), dim3(512), 131072, stream,
                       y, w3b, b3, out);
}